// Round 10
// baseline (207.280 us; speedup 1.0000x reference)
//
#include <hip/hip_runtime.h>

#define DIM   64
#define KCB   1024
#define NROW  32768

typedef float floatx4 __attribute__((ext_vector_type(4)));
typedef __bf16 bf16x8 __attribute__((ext_vector_type(8)));
typedef unsigned int uint;

union ABu { bf16x8 v; __bf16 h[8]; uint4 u4; };

// ---------------------------------------------------------------------------
// Prep (codebook only): fp32 codebook -> bf16 rows with 16B-chunk XOR swizzle
// (LDS image) + initv = -0.5*csq - 0.5 (makes every score < 0) + loss = 0.
// 128 blocks: thread = one 16B chunk (8 floats), csq via 8-lane shfl.
// (verified R7/R9)
// ---------------------------------------------------------------------------
extern "C" __global__ void __launch_bounds__(256)
vq_prep_cb(const float* __restrict__ cbg, uint* __restrict__ cb_bf,
           float* __restrict__ initv, float* __restrict__ loss)
{
    const int q = blockIdx.x * 256 + threadIdx.x;    // 0..32767 chunk-slots
    const int k = q >> 3;                            // codeword row 0..4095
    const int c = q & 7;                             // 16B chunk within row
    const float4* __restrict__ src = (const float4*)cbg + (size_t)k * 16 + c * 2;
    const float4 f0 = src[0];
    const float4 f1 = src[1];
    float csq = f0.x*f0.x + f0.y*f0.y + f0.z*f0.z + f0.w*f0.w
              + f1.x*f1.x + f1.y*f1.y + f1.z*f1.z + f1.w*f1.w;
    ABu t;
    t.h[0]=(__bf16)f0.x; t.h[1]=(__bf16)f0.y; t.h[2]=(__bf16)f0.z; t.h[3]=(__bf16)f0.w;
    t.h[4]=(__bf16)f1.x; t.h[5]=(__bf16)f1.y; t.h[6]=(__bf16)f1.z; t.h[7]=(__bf16)f1.w;
    const int dc = c ^ (k & 7);                      // LDS-bank XOR swizzle
    uint* __restrict__ drow = cb_bf + (size_t)k * 32;
    *(uint4*)&drow[dc * 4] = t.u4;
    csq += __shfl_xor(csq, 1);
    csq += __shfl_xor(csq, 2);
    csq += __shfl_xor(csq, 4);                       // sum over 8 chunks
    if (c == 0) initv[k] = -0.5f * csq - 0.5f;
    if (q == 0) *loss = 0.f;
}

// ---------------------------------------------------------------------------
// Fused score+emit, 4-way K-split + 2 COHORTS. Grid 1024 = chunk(8b, 128
// rows) | g(2b); 512 thr = 8 waves = 2 row-slices (rw, 64 rows, rt=4) x
// 4 K-quarters (kh, 256 cw). WHY: R7/R9 proved wins require BOTH rt=4 LDS
// economy (2 ds_read_b128 feed 8 MFMAs) AND 16 waves/CU; but grid 512 = one
// cohort -> chip-wide lockstep phases (A-read burst / K-loop / emit burst
// serialize: ~20us vs ~13us floor). Splitting K 4-ways halves the block to
// 128 rows -> grid 1024 = 2 cohorts at unchanged economy+occupancy: cohort
// 2's A-reads overlap cohort 1's K-loop + emit. Each kh stream: 4 tiles x
// 64 cw, double-buffered 2x8KB, DMA'd via global_load_lds issued before the
// current tile's MFMA; 3 mid barriers/block. Packed-key argmin in regs;
// 4-way combine via one LDS round. nt out stores (write-once; R9 verified).
// LDS ~70KB -> 2 blocks/CU. Codebook L2 traffic 2x (128MB, ~3.7us L2 agg,
// hidden under HBM); latent re-reads L2-hot.
// ---------------------------------------------------------------------------
extern "C" __global__ void __launch_bounds__(512, 4)
vq_score(const float* __restrict__ latents, const uint* __restrict__ cb_bf,
         const float* __restrict__ initv, const float* __restrict__ cbg,
         float* __restrict__ out, float* __restrict__ loss)
{
    __shared__ __attribute__((aligned(16))) uint  cb_lds[4][2][2048]; // 64 KB
    __shared__ __attribute__((aligned(16))) float iv_lds[KCB];        // 4 KB
    __shared__ uint  part_km[4][128];                                 // 2 KB
    __shared__ float xsq_lds[128];                                    // 512 B
    __shared__ float lsum_part[8];

    const int tid  = threadIdx.x;
    const int w    = tid >> 6;            // 0..7
    const int lane = tid & 63;
    const int l15  = lane & 15;
    const int quad = lane >> 4;
    const int kh   = w >> 1;              // K-quarter 0..3 (256 cw)
    const int rw   = w & 1;               // row-slice 0/1 (64 rows)

    const int bid   = blockIdx.x;
    const int chunk = bid & 255;          // bid%8 round-robins XCDs
    const int g     = bid >> 8;
    const int row0  = chunk * 128;
    const int wRow0 = row0 + rw * 64;

    // wave's K-quarter codebook image base (bf16, pre-swizzled), 256 cw
    const uint* gcb = cb_bf + (size_t)g * (KCB * 32) + (size_t)kh * (256 * 32);

    // ---- prologue: DMA tile0 (8KB/stream, half per rw-wave) + iv ----
    {
        #pragma unroll
        for (int i = 0; i < 4; ++i) {
            const int off = rw * 1024 + i * 256;             // uint words
            __builtin_amdgcn_global_load_lds(
                (const __attribute__((address_space(1))) uint*)(gcb + off + lane * 4),
                (__attribute__((address_space(3))) uint*)&cb_lds[kh][0][off], 16, 0, 0);
        }
        if (w < 4) {
            const uint* isrc = (const uint*)(initv + g * KCB) + w * 256;
            __builtin_amdgcn_global_load_lds(
                (const __attribute__((address_space(1))) uint*)(isrc + lane * 4),
                (__attribute__((address_space(3))) uint*)&iv_lds[w * 256], 16, 0, 0);
        }
    }

    // ---- A fragments from fp32 latents + xsq, in-register.
    // kh>0 waves re-read the same rows: L2-hot, cheaper than a sync.
    bf16x8 afrag[4][2];
    {
        const float4* __restrict__ lsrc = (const float4*)latents;
        #pragma unroll
        for (int rt = 0; rt < 4; ++rt) {
            const size_t rb = (size_t)(wRow0 + rt * 16 + l15) * 64 + g * 16
                            + (size_t)quad * 2;
            float s = 0.f;
            #pragma unroll
            for (int ks = 0; ks < 2; ++ks) {
                const float4 f0 = lsrc[rb + ks * 8];
                const float4 f1 = lsrc[rb + ks * 8 + 1];
                s += f0.x*f0.x + f0.y*f0.y + f0.z*f0.z + f0.w*f0.w
                   + f1.x*f1.x + f1.y*f1.y + f1.z*f1.z + f1.w*f1.w;
                ABu t;
                t.h[0]=(__bf16)f0.x; t.h[1]=(__bf16)f0.y; t.h[2]=(__bf16)f0.z; t.h[3]=(__bf16)f0.w;
                t.h[4]=(__bf16)f1.x; t.h[5]=(__bf16)f1.y; t.h[6]=(__bf16)f1.z; t.h[7]=(__bf16)f1.w;
                afrag[rt][ks] = t.v;
            }
            s += __shfl_xor(s, 16);
            s += __shfl_xor(s, 32);       // full 64-dim row sum
            if (kh == 0 && quad == 0) xsq_lds[rw * 64 + rt * 16 + l15] = s;
        }
    }
    __syncthreads();                      // tile0 (all streams) + iv + xsq

    uint best[4][4];
    #pragma unroll
    for (int rt = 0; rt < 4; ++rt)
        #pragma unroll
        for (int r = 0; r < 4; ++r) best[rt][r] = 0xFFFFFFFFu;

    const int o0  = l15 * 32;
    const int sw0 = (quad       ^ (l15 & 7)) << 2;
    const int sw1 = ((quad + 4) ^ (l15 & 7)) << 2;

    #pragma unroll
    for (int tile = 0; tile < 4; ++tile) {
        // issue next tile's DMA first: overlaps the 4 t-iters of MFMA below
        if (tile < 3) {
            const uint* gsrc = gcb + (tile + 1) * 2048;      // 64 cw tiles
            #pragma unroll
            for (int i = 0; i < 4; ++i) {
                const int off = rw * 1024 + i * 256;
                __builtin_amdgcn_global_load_lds(
                    (const __attribute__((address_space(1))) uint*)(gsrc + off + lane * 4),
                    (__attribute__((address_space(3))) uint*)&cb_lds[kh][(tile + 1) & 1][off], 16, 0, 0);
            }
        }

        const uint*  bbase0 = &cb_lds[kh][tile & 1][o0 + sw0];
        const uint*  bbase1 = &cb_lds[kh][tile & 1][o0 + sw1];
        const float* ivb    = &iv_lds[kh * 256 + tile * 64 + l15];
        const uint   kcol0  = (uint)(kh * 256 + tile * 64 + l15);

        #pragma unroll
        for (int t = 0; t < 4; ++t) {
            const float v = ivb[t * 16];
            ABu b0, b1;
            b0.u4 = *(const uint4*)(bbase0 + t * 512);
            b1.u4 = *(const uint4*)(bbase1 + t * 512);
            const uint kcol = kcol0 + t * 16;
            const floatx4 accb = { v, v, v, v };   // shared C operand (D != C)
            #pragma unroll
            for (int rt = 0; rt < 4; ++rt) {
                floatx4 acc = __builtin_amdgcn_mfma_f32_16x16x32_bf16(afrag[rt][0], b0.v, accb, 0, 0, 0);
                acc = __builtin_amdgcn_mfma_f32_16x16x32_bf16(afrag[rt][1], b1.v, acc, 0, 0, 0);
                // score < 0 -> fp32 bits monotone decreasing; pack idx, min_u32
                #pragma unroll
                for (int r = 0; r < 4; ++r) {
                    const uint key = (__float_as_uint(acc[r]) & 0xFFFFFC00u) | kcol;
                    best[rt][r] = best[rt][r] < key ? best[rt][r] : key;
                }
            }
        }
        if (tile < 3) __syncthreads();    // drains next-tile DMA + frees buf
    }

    // ---- per-wave 16-lane column reduce -> K-quarter partial keys ----
    #pragma unroll
    for (int rt = 0; rt < 4; ++rt)
        #pragma unroll
        for (int r = 0; r < 4; ++r) {
            uint kmin = best[rt][r];
            #pragma unroll
            for (int m = 1; m <= 8; m <<= 1) {
                const uint o = (uint)__shfl_xor((int)kmin, m);
                kmin = o < kmin ? o : kmin;
            }
            if (l15 == 0)
                part_km[kh][rw * 64 + rt * 16 + quad * 4 + r] = kmin;
        }
    __syncthreads();

    // ---- emit: combine K-quarters, gather fp32 codeword, out + loss ----
    float lsum = 0.f;
    const float4* __restrict__ cb4 = (const float4*)cbg + (size_t)g * (KCB * 16);
    float4* __restrict__ out4 = (float4*)out;
    #pragma unroll
    for (int jj = 0; jj < 4; ++jj) {
        const int row = w * 16 + jj * 4 + quad;             // block-local row
        const uint k0 = part_km[0][row];
        const uint k1 = part_km[1][row];
        const uint k2 = part_km[2][row];
        const uint k3 = part_km[3][row];
        uint kmin = k0 < k1 ? k0 : k1;
        const uint km2 = k2 < k3 ? k2 : k3;
        kmin = kmin < km2 ? kmin : km2;
        const int kidx = (int)(kmin & 1023u);
        // 16 lanes x float4 = 256B/row; 4 rows/instr = dense 1KB wave writes.
        // NON-TEMPORAL: out is write-once -> don't evict L2-hot cb/latents.
        const float4 cw = cb4[(size_t)kidx * 16 + l15];
        __builtin_nontemporal_store(*(const floatx4*)&cw,
            (floatx4*)&out4[(size_t)(row0 + row) * 64 + g * 16 + l15]);
        if (l15 == 0) {
            const float sc = __uint_as_float(kmin & 0xFFFFFC00u);
            lsum += xsq_lds[row] - 2.f * sc - 1.f;          // exact sq dist
        }
    }
    lsum += __shfl_xor(lsum, 16);
    lsum += __shfl_xor(lsum, 32);         // sum the 4 quad partials
    if (lane == 0) lsum_part[w] = lsum;
    __syncthreads();
    if (tid == 0) {
        float t = 0.f;
        #pragma unroll
        for (int i = 0; i < 8; ++i) t += lsum_part[i];
        atomicAdd(loss, t * (1.25f / 8388608.0f));
    }
}

extern "C" void kernel_launch(void* const* d_in, const int* in_sizes, int n_in,
                              void* d_out, int out_size, void* d_ws, size_t ws_size,
                              hipStream_t stream)
{
    const float* latents = (const float*)d_in[0];
    const float* cbg     = (const float*)d_in[1];
    float* out   = (float*)d_out;
    float* lossp = out + 8388608;

    uint*  cb_bf = (uint*)d_ws;                          // 512 KB
    float* initv = (float*)((uint*)d_ws + 4096 * 32);    // 16 KB

    vq_prep_cb<<<dim3(128),  dim3(256), 0, stream>>>(cbg, cb_bf, initv, lossp);
    vq_score  <<<dim3(1024), dim3(512), 0, stream>>>(latents, cb_bf, initv,
                                                     cbg, out, lossp);
}

// Round 11
// 109.688 us; speedup vs baseline: 1.8897x; 1.8897x over previous
//
#include <hip/hip_runtime.h>

#define DIM   64
#define KCB   1024
#define KT2   128    // codewords per LDS tile
#define NROW  32768

typedef float floatx4 __attribute__((ext_vector_type(4)));
typedef __bf16 bf16x8 __attribute__((ext_vector_type(8)));
typedef unsigned int uint;

union ABu { bf16x8 v; __bf16 h[8]; uint4 u4; };

// ---------------------------------------------------------------------------
// Prep (codebook only): fp32 codebook -> bf16 rows with 16B-chunk XOR swizzle
// (LDS image) + initv = -0.5*csq - 0.5 (makes every score < 0) + loss = 0.
// 128 blocks: thread = one 16B chunk (8 floats), csq via 8-lane shfl.
// (verified R7/R9)
// ---------------------------------------------------------------------------
extern "C" __global__ void __launch_bounds__(256)
vq_prep_cb(const float* __restrict__ cbg, uint* __restrict__ cb_bf,
           float* __restrict__ initv, float* __restrict__ loss)
{
    const int q = blockIdx.x * 256 + threadIdx.x;    // 0..32767 chunk-slots
    const int k = q >> 3;                            // codeword row 0..4095
    const int c = q & 7;                             // 16B chunk within row
    const float4* __restrict__ src = (const float4*)cbg + (size_t)k * 16 + c * 2;
    const float4 f0 = src[0];
    const float4 f1 = src[1];
    float csq = f0.x*f0.x + f0.y*f0.y + f0.z*f0.z + f0.w*f0.w
              + f1.x*f1.x + f1.y*f1.y + f1.z*f1.z + f1.w*f1.w;
    ABu t;
    t.h[0]=(__bf16)f0.x; t.h[1]=(__bf16)f0.y; t.h[2]=(__bf16)f0.z; t.h[3]=(__bf16)f0.w;
    t.h[4]=(__bf16)f1.x; t.h[5]=(__bf16)f1.y; t.h[6]=(__bf16)f1.z; t.h[7]=(__bf16)f1.w;
    const int dc = c ^ (k & 7);                      // LDS-bank XOR swizzle
    uint* __restrict__ drow = cb_bf + (size_t)k * 32;
    *(uint4*)&drow[dc * 4] = t.u4;
    csq += __shfl_xor(csq, 1);
    csq += __shfl_xor(csq, 2);
    csq += __shfl_xor(csq, 4);                       // sum over 8 chunks
    if (c == 0) initv[k] = -0.5f * csq - 0.5f;
    if (q == 0) *loss = 0.f;
}

// ---------------------------------------------------------------------------
// Fused score+emit, K-SPLIT waves (R7/R9 verified structure — terminal).
// Grid 512 = chunk(7b, 256 rows) | g(2b); 512 thr = 8 waves = 4 row-slices
// (rt=4, 64 rows) x 2 K-halves (512 cw each). Each K-half has its own
// double-buffered 2x16KB LDS tile stream (4 barriers/block); 2 ds_read_b128
// feed 8 MFMAs (LDS-pipe 6.4us/CU < MFMA 8.3us); packed-key argmin in regs;
// K-halves combine via one LDS round. nt out stores (write-once; R9: -1.8us).
// VGPR 64, 2 blocks/CU, 16 waves/CU.
// Load-bearing invariants (measured across R3-R10; breaking any regresses):
//  * rt=4 LDS economy (R4: rt=1 -> LDS-read-bound, +29us)
//  * 16 waves/CU     (R5: 8 waves -> latency-bound, +10us)
//  * latent sharing stays intra-block, <=2 streams (R10: 4-way -> L2 thrash,
//    FETCH 181MB, +97us)
//  * no codebook-in-regs (R6: VGPR spill, +32us)
//  * no inline-asm vmcnt in unrolled loop (R8: scratch-pinned accs, +308us)
// ---------------------------------------------------------------------------
extern "C" __global__ void __launch_bounds__(512, 4)
vq_score(const float* __restrict__ latents, const uint* __restrict__ cb_bf,
         const float* __restrict__ initv, const float* __restrict__ cbg,
         float* __restrict__ out, float* __restrict__ loss)
{
    __shared__ __attribute__((aligned(16))) uint  cb_lds[2][2][KT2 * 32]; // 64KB
    __shared__ __attribute__((aligned(16))) float iv_lds[KCB];            // 4KB
    __shared__ uint  part_km[2][256];                                     // 2KB
    __shared__ float xsq_lds[256];                                        // 1KB
    __shared__ float lsum_part[8];

    const int tid  = threadIdx.x;
    const int w    = tid >> 6;            // 0..7
    const int lane = tid & 63;
    const int l15  = lane & 15;
    const int quad = lane >> 4;
    const int kh   = w >> 2;              // K-half 0/1 (512 cw)
    const int rw   = w & 3;               // row-slice 0..3 (64 rows)

    const int bid   = blockIdx.x;
    const int chunk = bid & 127;          // bid%8 round-robins XCDs; the 4
    const int g     = bid >> 7;           // g-siblings share latent rows in L2
    const int row0  = chunk * 256;
    const int wRow0 = row0 + rw * 64;

    // wave's K-half codebook image base (bf16, pre-swizzled)
    const uint* gcb = cb_bf + (size_t)g * (KCB * 32) + (size_t)kh * (512 * 32);

    // ---- prologue: DMA tile0 of this wave's stream + iv (waves 0-3) ----
    {
        #pragma unroll
        for (int i = 0; i < 4; ++i) {
            const int off = rw * 1024 + i * 256;             // uint words
            __builtin_amdgcn_global_load_lds(
                (const __attribute__((address_space(1))) uint*)(gcb + off + lane * 4),
                (__attribute__((address_space(3))) uint*)&cb_lds[kh][0][off], 16, 0, 0);
        }
        if (kh == 0) {
            const uint* isrc = (const uint*)(initv + g * KCB) + rw * 256;
            __builtin_amdgcn_global_load_lds(
                (const __attribute__((address_space(1))) uint*)(isrc + lane * 4),
                (__attribute__((address_space(3))) uint*)&iv_lds[rw * 256], 16, 0, 0);
        }
    }

    // ---- A fragments from fp32 latents + xsq, in-register (loop-invariant).
    // kh=1 waves re-load the same rows as kh=0: L2-hot, cheaper than a sync.
    bf16x8 afrag[4][2];
    {
        const float4* __restrict__ lsrc = (const float4*)latents;
        #pragma unroll
        for (int rt = 0; rt < 4; ++rt) {
            const size_t rb = (size_t)(wRow0 + rt * 16 + l15) * 64 + g * 16
                            + (size_t)quad * 2;
            float s = 0.f;
            #pragma unroll
            for (int ks = 0; ks < 2; ++ks) {
                const float4 f0 = lsrc[rb + ks * 8];
                const float4 f1 = lsrc[rb + ks * 8 + 1];
                s += f0.x*f0.x + f0.y*f0.y + f0.z*f0.z + f0.w*f0.w
                   + f1.x*f1.x + f1.y*f1.y + f1.z*f1.z + f1.w*f1.w;
                ABu t;
                t.h[0]=(__bf16)f0.x; t.h[1]=(__bf16)f0.y; t.h[2]=(__bf16)f0.z; t.h[3]=(__bf16)f0.w;
                t.h[4]=(__bf16)f1.x; t.h[5]=(__bf16)f1.y; t.h[6]=(__bf16)f1.z; t.h[7]=(__bf16)f1.w;
                afrag[rt][ks] = t.v;
            }
            s += __shfl_xor(s, 16);
            s += __shfl_xor(s, 32);       // full 64-dim row sum
            if (kh == 0 && quad == 0) xsq_lds[rw * 64 + rt * 16 + l15] = s;
        }
    }
    __syncthreads();                      // tile0 (both streams) + iv + xsq

    uint best[4][4];
    #pragma unroll
    for (int rt = 0; rt < 4; ++rt)
        #pragma unroll
        for (int r = 0; r < 4; ++r) best[rt][r] = 0xFFFFFFFFu;

    const int o0  = l15 * 32;
    const int sw0 = (quad       ^ (l15 & 7)) << 2;
    const int sw1 = ((quad + 4) ^ (l15 & 7)) << 2;

    #pragma unroll
    for (int tile = 0; tile < 4; ++tile) {
        // issue next tile's DMA first: overlaps the 8 t-iters of MFMA below
        if (tile < 3) {
            const uint* gsrc = gcb + (tile + 1) * (KT2 * 32);
            #pragma unroll
            for (int i = 0; i < 4; ++i) {
                const int off = rw * 1024 + i * 256;
                __builtin_amdgcn_global_load_lds(
                    (const __attribute__((address_space(1))) uint*)(gsrc + off + lane * 4),
                    (__attribute__((address_space(3))) uint*)&cb_lds[kh][(tile + 1) & 1][off], 16, 0, 0);
            }
        }

        const uint*  bbase0 = &cb_lds[kh][tile & 1][o0 + sw0];
        const uint*  bbase1 = &cb_lds[kh][tile & 1][o0 + sw1];
        const float* ivb    = &iv_lds[kh * 512 + tile * KT2 + l15];
        const uint   kcol0  = (uint)(kh * 512 + tile * KT2 + l15);

        #pragma unroll 2
        for (int t = 0; t < 8; ++t) {
            const float v = ivb[t * 16];
            ABu b0, b1;
            b0.u4 = *(const uint4*)(bbase0 + t * 512);
            b1.u4 = *(const uint4*)(bbase1 + t * 512);
            const uint kcol = kcol0 + t * 16;
            const floatx4 accb = { v, v, v, v };   // shared C operand (D != C)
            #pragma unroll
            for (int rt = 0; rt < 4; ++rt) {
                floatx4 acc = __builtin_amdgcn_mfma_f32_16x16x32_bf16(afrag[rt][0], b0.v, accb, 0, 0, 0);
                acc = __builtin_amdgcn_mfma_f32_16x16x32_bf16(afrag[rt][1], b1.v, acc, 0, 0, 0);
                // score < 0 -> fp32 bits monotone decreasing; pack idx, min_u32
                #pragma unroll
                for (int r = 0; r < 4; ++r) {
                    const uint key = (__float_as_uint(acc[r]) & 0xFFFFFC00u) | kcol;
                    best[rt][r] = best[rt][r] < key ? best[rt][r] : key;
                }
            }
        }
        if (tile < 3) __syncthreads();    // drains next-tile DMA + frees buf
    }

    // ---- per-wave 16-lane column reduce -> K-half partial keys ----
    #pragma unroll
    for (int rt = 0; rt < 4; ++rt)
        #pragma unroll
        for (int r = 0; r < 4; ++r) {
            uint kmin = best[rt][r];
            #pragma unroll
            for (int m = 1; m <= 8; m <<= 1) {
                const uint o = (uint)__shfl_xor((int)kmin, m);
                kmin = o < kmin ? o : kmin;
            }
            if (l15 == 0)
                part_km[kh][rw * 64 + rt * 16 + quad * 4 + r] = kmin;
        }
    __syncthreads();

    // ---- emit: combine K-halves, gather fp32 codeword, write out + loss ----
    float lsum = 0.f;
    const float4* __restrict__ cb4 = (const float4*)cbg + (size_t)g * (KCB * 16);
    float4* __restrict__ out4 = (float4*)out;
    #pragma unroll
    for (int jj = 0; jj < 8; ++jj) {
        const int row = w * 32 + jj * 4 + quad;             // block-local row
        const uint k0 = part_km[0][row];
        const uint k1 = part_km[1][row];
        const uint kmin = k0 < k1 ? k0 : k1;
        const int  kidx = (int)(kmin & 1023u);
        // 16 lanes x float4 = 256B/row; 4 rows/instr = dense 1KB wave writes.
        // NON-TEMPORAL: out is write-once -> don't evict L2-hot cb/latents.
        const float4 cw = cb4[(size_t)kidx * 16 + l15];
        __builtin_nontemporal_store(*(const floatx4*)&cw,
            (floatx4*)&out4[(size_t)(row0 + row) * 64 + g * 16 + l15]);
        if (l15 == 0) {
            const float sc = __uint_as_float(kmin & 0xFFFFFC00u);
            lsum += xsq_lds[row] - 2.f * sc - 1.f;          // exact sq dist
        }
    }
    lsum += __shfl_xor(lsum, 16);
    lsum += __shfl_xor(lsum, 32);         // sum the 4 quad partials
    if (lane == 0) lsum_part[w] = lsum;
    __syncthreads();
    if (tid == 0) {
        float t = 0.f;
        #pragma unroll
        for (int i = 0; i < 8; ++i) t += lsum_part[i];
        atomicAdd(loss, t * (1.25f / 8388608.0f));
    }
}

extern "C" void kernel_launch(void* const* d_in, const int* in_sizes, int n_in,
                              void* d_out, int out_size, void* d_ws, size_t ws_size,
                              hipStream_t stream)
{
    const float* latents = (const float*)d_in[0];
    const float* cbg     = (const float*)d_in[1];
    float* out   = (float*)d_out;
    float* lossp = out + 8388608;

    uint*  cb_bf = (uint*)d_ws;                          // 512 KB
    float* initv = (float*)((uint*)d_ws + 4096 * 32);    // 16 KB

    vq_prep_cb<<<dim3(128), dim3(256), 0, stream>>>(cbg, cb_bf, initv, lossp);
    vq_score  <<<dim3(512), dim3(512), 0, stream>>>(latents, cb_bf, initv,
                                                    cbg, out, lossp);
}